// Round 6
// baseline (409.557 us; speedup 1.0000x reference)
//
#include <hip/hip_runtime.h>
#include <hip/hip_fp16.h>
#include <math.h>

#define BB 8
#define CC 1024
#define LL 4096
#define NPB (CC*LL)          // 4194304 elements per batch
#define LT 32                // l-tile per fused block (32 floats = full 128B lines)

typedef float f32x4 __attribute__((ext_vector_type(4)));

// ws layout:
//   [0,128)    double sums[16]      (S1,S2 per batch)
//   [128,136)  double lossAcc

// grid (256, 8) x 256 threads. Each thread: 16 float4 of xt, strided, unroll 4.
// Side effect we rely on: pulls all of x_st (134 MB) into L3.
__global__ void k_batch_sums(const float* __restrict__ xt, double* __restrict__ sums) {
    int b = blockIdx.y;
    const float4* p = (const float4*)(xt + (size_t)b * NPB);
    int t = blockIdx.x * blockDim.x + threadIdx.x;      // [0, 65536)
    double s1 = 0.0, s2 = 0.0;
    #pragma unroll
    for (int j4 = 0; j4 < 4; ++j4) {
        float4 v[4];
        #pragma unroll
        for (int k = 0; k < 4; ++k) v[k] = p[(size_t)(j4 * 4 + k) * 65536 + t];
        #pragma unroll
        for (int k = 0; k < 4; ++k) {
            float q1 = (v[k].x + v[k].y) + (v[k].z + v[k].w);
            float q2 = (v[k].x * v[k].x + v[k].y * v[k].y)
                     + (v[k].z * v[k].z + v[k].w * v[k].w);
            s1 += (double)q1;
            s2 += (double)q2;
        }
    }
    for (int off = 32; off; off >>= 1) {
        s1 += __shfl_down(s1, off, 64);
        s2 += __shfl_down(s2, off, 64);
    }
    __shared__ double ls1[4], ls2[4];
    int lane = threadIdx.x & 63, w = threadIdx.x >> 6;
    if (lane == 0) { ls1[w] = s1; ls2[w] = s2; }
    __syncthreads();
    if (threadIdx.x == 0) {
        atomicAdd(&sums[2 * b],     ls1[0] + ls1[1] + ls1[2] + ls1[3]);
        atomicAdd(&sums[2 * b + 1], ls2[0] + ls2[1] + ls2[2] + ls2[3]);
    }
}

// Fused colstats + entropy, register-resident variant (ZERO pass-2 global loads).
// grid (LL/LT=128, 8) x 1024 threads (16 waves). Block owns (b, l in [L0,L0+32))
// for ALL C=1024 channels. Thread: q=tid&7 -> l-quad; g=tid>>3 -> c=g+128i, i<8.
// Per c, 8 consecutive lanes x float4 = 128 B = exactly one cache line.
//
// Payload across the barrier: es[8] f32 (32 VGPR) + y packed fp16 (16 VGPR) =
// 48 regs -> fits the 64-reg/8-wave-EU budget the compiler insists on
// (r1..r5: it picks 52-60 VGPR regardless of granted budget). fp16-y error:
// ulp(y~5)=3.9e-3, Δe = p*Δy <= 0.05*2e-3 = 1e-4 << the ~1e-3 tolerance.
//
// Barrier diet: margin is computed per-thread (redundant ~30 f64 ops, hidden
// under the 16 in-flight loads) -- no broadcast barrier. After the ONE
// barrier, every thread reduces the 16 wave-partials from LDS itself
// (ds_read_b128 broadcast, conflict-free) -- no tid<64 stage, no 3rd barrier.
// NOTE: the +25% on WRITE_SIZE is misaligned-store amplification (out+1, every
// 128B segment spans 5 sectors) -- NOT scratch spill; r2's theory was wrong.
__global__ __launch_bounds__(1024)
void k_fused(const float* __restrict__ xs, const float* __restrict__ xt,
             const double* __restrict__ sums,
             float* __restrict__ out1, double* __restrict__ lossAcc) {
    int tid = threadIdx.x;
    int b = blockIdx.y;
    int L0 = blockIdx.x * LT;
    int q = tid & 7;
    int g = tid >> 3;
    int lane = tid & 63, w = tid >> 6;

    __shared__ __align__(16) float s_red[2][16][8][4];   // [arr][wave][q][k]
    __shared__ float wacc[16];

    const float* ps = xs + (size_t)b * NPB + L0 + q * 4;
    const float* pt = xt + (size_t)b * NPB + L0 + q * 4;

    // ---- issue all 16 loads first; margin math hides under their latency ----
    f32x4 s4[8];
    float4 t4[8];
    #pragma unroll
    for (int i = 0; i < 8; ++i) {
        size_t off = (size_t)(g + 128 * i) * LL;
        s4[i] = __builtin_nontemporal_load((const f32x4*)(ps + off));  // xs: read-once, keep out of L3
        t4[i] = *(const float4*)(pt + off);                            // xt: L3-warm from k_batch_sums
    }

    // margin, computed redundantly by every thread (no barrier, no LDS)
    float mg;
    {
        double n = (double)NPB;
        double s1 = sums[2 * b], s2 = sums[2 * b + 1];
        double mean = s1 / n;
        double var = (s2 - s1 * s1 / n) / (n - 1.0);     // ddof=1
        double sd = sqrt(var);
        double z = -mean / sd;
        double cdf = 0.5 * (1.0 + erf(z / 1.4142135623730951));
        double safe = fmax(cdf, 1e-30);
        double r = mean / sd;
        double ma = -sd * exp(-r * r * 0.5) / 2.5066282746310002 / safe + mean;
        mg = (float)((cdf > 0.001) ? ma : -3.0 * sd);
    }

    float4 es[8];
    __half2 yh[16];
    float ss[4] = {0, 0, 0, 0}, sy[4] = {0, 0, 0, 0};
    #pragma unroll
    for (int i = 0; i < 8; ++i) {
        float4 e;
        e.x = __expf(s4[i].x); e.y = __expf(s4[i].y);
        e.z = __expf(s4[i].z); e.w = __expf(s4[i].w);
        es[i] = e;
        ss[0] += e.x; ss[1] += e.y; ss[2] += e.z; ss[3] += e.w;
        float y0 = fmaxf(t4[i].x, mg), y1 = fmaxf(t4[i].y, mg);
        float y2 = fmaxf(t4[i].z, mg), y3 = fmaxf(t4[i].w, mg);
        sy[0] += __expf(y0); sy[1] += __expf(y1);
        sy[2] += __expf(y2); sy[3] += __expf(y3);
        yh[2 * i]     = __floats2half2_rn(y0, y1);   // fp16 payload: 2 regs per 4 y
        yh[2 * i + 1] = __floats2half2_rn(y2, y3);
    }
    // reduce across the 8 c-groups inside each wave (same-q lanes: lane = q + 8*gg)
    #pragma unroll
    for (int off = 8; off < 64; off <<= 1) {
        #pragma unroll
        for (int k = 0; k < 4; ++k) {
            ss[k] += __shfl_xor(ss[k], off, 64);
            sy[k] += __shfl_xor(sy[k], off, 64);
        }
    }
    if (lane < 8) {                      // lane == q for lane<8
        #pragma unroll
        for (int k = 0; k < 4; ++k) {
            s_red[0][w][lane][k] = ss[k];
            s_red[1][w][lane][k] = sy[k];
        }
    }
    __syncthreads();                     // the ONE hot-path barrier

    // every thread reduces the 16 wave-partials itself (broadcast ds_read_b128;
    // 8 distinct 16B lines per wave -> all 32 banks hit once, conflict-free)
    float ssT[4] = {0, 0, 0, 0}, syT[4] = {0, 0, 0, 0};
    #pragma unroll
    for (int ww = 0; ww < 16; ++ww) {
        float4 a = *(const float4*)&s_red[0][ww][q][0];
        float4 c = *(const float4*)&s_red[1][ww][q][0];
        ssT[0] += a.x; ssT[1] += a.y; ssT[2] += a.z; ssT[3] += a.w;
        syT[0] += c.x; syT[1] += c.y; syT[2] += c.z; syT[3] += c.w;
    }
    float4 sinv, blog;
    sinv.x = 1.0f / ssT[0]; sinv.y = 1.0f / ssT[1];
    sinv.z = 1.0f / ssT[2]; sinv.w = 1.0f / ssT[3];
    blog.x = __logf(syT[0]); blog.y = __logf(syT[1]);
    blog.z = __logf(syT[2]); blog.w = __logf(syT[3]);

    // ---- pass 2: pure register compute + NT stores, zero global loads ----
    float* po = out1 + (size_t)b * NPB + L0 + q * 4;
    float acc = 0.f;
    #pragma unroll
    for (int i = 0; i < 8; ++i) {
        size_t off = (size_t)(g + 128 * i) * LL;
        float2 ylo = __half22float2(yh[2 * i]);
        float2 yhi = __half22float2(yh[2 * i + 1]);
        f32x4 e;
        e.x = es[i].x * sinv.x * (ylo.x - blog.x);
        e.y = es[i].y * sinv.y * (ylo.y - blog.y);
        e.z = es[i].z * sinv.z * (yhi.x - blog.z);
        e.w = es[i].w * sinv.w * (yhi.y - blog.w);
        __builtin_nontemporal_store(e, (f32x4*)(po + off));  // don't evict xt from L3
        acc += (e.x + e.y) + (e.z + e.w);
    }
    for (int off = 32; off; off >>= 1) acc += __shfl_down(acc, off, 64);
    if (lane == 0) wacc[w] = acc;
    __syncthreads();
    if (tid == 0) {
        double t = 0.0;
        #pragma unroll
        for (int ww = 0; ww < 16; ++ww) t += (double)wacc[ww];
        atomicAdd(lossAcc, t);
    }
}

__global__ void k_finalize(const double* __restrict__ lossAcc, float* __restrict__ out) {
    if (threadIdx.x == 0) out[0] = (float)(-lossAcc[0] / (double)(BB * LL));
}

extern "C" void kernel_launch(void* const* d_in, const int* in_sizes, int n_in,
                              void* d_out, int out_size, void* d_ws, size_t ws_size,
                              hipStream_t stream) {
    const float* x_ts = (const float*)d_in[2];  // source xs
    const float* x_st = (const float*)d_in[3];  // target xt
    float* out = (float*)d_out;

    double* sums    = (double*)d_ws;
    double* lossAcc = (double*)((char*)d_ws + 128);

    hipMemsetAsync(d_ws, 0, 256, stream);

    k_batch_sums<<<dim3(256, BB), 256, 0, stream>>>(x_st, sums);
    k_fused<<<dim3(LL / LT, BB), 1024, 0, stream>>>(x_ts, x_st, sums, out + 1, lossAcc);
    k_finalize<<<1, 64, 0, stream>>>(lossAcc, out);
}